// Round 7
// baseline (15049.152 us; speedup 1.0000x reference)
//
#include <hip/hip_runtime.h>

#define TPB 256
#define GRP 8
#define NPB (TPB / GRP)   // 32 nodes per block

typedef unsigned int uint;

// ---------------------------------------------------------------------------
// prep: pad x to float4 for single-load gathers
// ---------------------------------------------------------------------------
__global__ __launch_bounds__(256) void prep_kernel(
    const float* __restrict__ x, float4* __restrict__ xp, int N)
{
    int n = blockIdx.x * 256 + threadIdx.x;
    if (n < N) xp[n] = make_float4(x[3*n], x[3*n+1], x[3*n+2], 0.f);
}

// ---------------------------------------------------------------------------
// counting sort by row: hist -> (bsum, scan_small, scan_final) -> scatter
// ---------------------------------------------------------------------------
__global__ __launch_bounds__(256) void hist_kernel(
    const int* __restrict__ ei, uint* __restrict__ cnt, int E)
{
    int e = blockIdx.x * 256 + threadIdx.x;
    if (e < E) atomicAdd(&cnt[ei[e]], 1u);
}

__global__ __launch_bounds__(256) void bsum_kernel(
    const uint* __restrict__ cnt, uint* __restrict__ bsum, int N)
{
    __shared__ uint lds[256];
    int b = blockIdx.x, t = threadIdx.x;
    int base = b * 1024;
    uint s = 0;
    for (int k = 0; k < 4; ++k) {
        int i = base + t + k * 256;
        if (i < N) s += cnt[i];
    }
    lds[t] = s; __syncthreads();
    for (int st = 128; st > 0; st >>= 1) {
        if (t < st) lds[t] += lds[t + st];
        __syncthreads();
    }
    if (t == 0) bsum[b] = lds[0];
}

__global__ __launch_bounds__(1024) void scan_small_kernel(
    const uint* __restrict__ bsum, uint* __restrict__ boff,
    uint* __restrict__ off, int nb, int N, int E)
{
    __shared__ uint lds[1024];
    int t = threadIdx.x;
    uint v = (t < nb) ? bsum[t] : 0u;
    lds[t] = v; __syncthreads();
    for (int st = 1; st < 1024; st <<= 1) {
        uint u = (t >= st) ? lds[t - st] : 0u;
        __syncthreads();
        lds[t] += u; __syncthreads();
    }
    if (t < nb) boff[t] = lds[t] - v;
    if (t == 0) off[N] = (uint)E;
}

__global__ __launch_bounds__(256) void scan_final_kernel(
    const uint* __restrict__ cnt, const uint* __restrict__ boff,
    uint* __restrict__ off, uint* __restrict__ cur, int N)
{
    __shared__ uint lds[256];
    int b = blockIdx.x, t = threadIdx.x;
    int base = b * 1024;
    uint vals[4]; uint s = 0;
    for (int k = 0; k < 4; ++k) {
        int i = base + t * 4 + k;
        vals[k] = (i < N) ? cnt[i] : 0u;
        s += vals[k];
    }
    lds[t] = s; __syncthreads();
    for (int st = 1; st < 256; st <<= 1) {
        uint u = (t >= st) ? lds[t - st] : 0u;
        __syncthreads();
        lds[t] += u; __syncthreads();
    }
    uint run = boff[b] + lds[t] - s;
    for (int k = 0; k < 4; ++k) {
        int i = base + t * 4 + k;
        if (i < N) { off[i] = run; cur[i] = run; }
        run += vals[k];
    }
}

// Plan A: scatter full edge payload {ea0,ea1,ea2,col} into row-sorted position
__global__ __launch_bounds__(256) void scatter_payload_kernel(
    const int* __restrict__ ei, const float* __restrict__ ea,
    uint* __restrict__ cur, float4* __restrict__ data, int E)
{
    int e = blockIdx.x * 256 + threadIdx.x;
    if (e >= E) return;
    int r = ei[e], c = ei[E + e];
    uint p = atomicAdd(&cur[r], 1u);
    data[p] = make_float4(ea[3*e], ea[3*e+1], ea[3*e+2], __int_as_float(c));
}

// Plan B: scatter only the edge index (perm) — 4x less workspace
__global__ __launch_bounds__(256) void scatter_perm_kernel(
    const int* __restrict__ ei, uint* __restrict__ cur,
    uint* __restrict__ perm, int E)
{
    int e = blockIdx.x * 256 + threadIdx.x;
    if (e < E) {
        uint p = atomicAdd(&cur[ei[e]], 1u);
        perm[p] = (uint)e;
    }
}

// ---------------------------------------------------------------------------
// Node-centric fused MLP kernel. 8 lanes per node, ONE edge per lane per iter
// (R6's 2-edge blocking spilled: VGPR 256 + 13.9 GB scratch traffic).
// Weights in LDS, transposed + padded for ds_read_b128 at compile-time
// offsets. Node-MLP layer2 applied once per node after the 8-lane reduce.
// Per-block LDS graph accumulator (batch sorted) -> few global atomics.
// W layout (floats): EW1T[50][12]@0 (w0..w8,b,pad2) | EW2P[50][16]@600
//   (15w,pad) | NW1T[50][20]@1400 (3xc,15e2,b,pad) | NW2T[15][53]@2400
//   (50w,b,pad2) | EB2[15]@3195
// ---------------------------------------------------------------------------
template<bool PAYLOAD>
__global__ __launch_bounds__(TPB) void node_kernel(
    const float4* __restrict__ xp, const float4* __restrict__ data,
    const uint* __restrict__ perm,
    const int* __restrict__ ei, const float* __restrict__ ea,
    const uint* __restrict__ off, const int* __restrict__ batch,
    const float* __restrict__ ew1, const float* __restrict__ eb1,
    const float* __restrict__ ew2, const float* __restrict__ eb2,
    const float* __restrict__ nw1, const float* __restrict__ nb1,
    const float* __restrict__ nw2, const float* __restrict__ nb2,
    float* __restrict__ g_acc, int N, int E)
{
    __shared__ float W[3216];
    __shared__ float gl[NPB + 1][16];
    const int t = threadIdx.x;

    for (int idx = t; idx < 600; idx += TPB) {            // EW1T
        int j = idx / 12, p = idx - j * 12;
        float v = 0.f;
        if (p < 9) v = ew1[p * 50 + j];
        else if (p == 9) v = eb1[j];
        W[idx] = v;
    }
    for (int idx = t; idx < 800; idx += TPB) {            // EW2P
        int j = idx / 16, k = idx - j * 16;
        W[600 + idx] = (k < 15) ? ew2[j * 15 + k] : 0.f;
    }
    for (int idx = t; idx < 1000; idx += TPB) {           // NW1T
        int j = idx / 20, p = idx - j * 20;
        float v = 0.f;
        if (p < 18) v = nw1[p * 50 + j];
        else if (p == 18) v = nb1[j];
        W[1400 + idx] = v;
    }
    for (int idx = t; idx < 795; idx += TPB) {            // NW2T
        int jj = idx / 53, p = idx - jj * 53;
        float v = 0.f;
        if (p < 50) v = nw2[p * 15 + jj];
        else if (p == 50) v = nb2[jj];
        W[2400 + idx] = v;
    }
    if (t < 15) W[3195 + t] = eb2[t];
    for (int idx = t; idx < (NPB + 1) * 16; idx += TPB)
        ((float*)gl)[idx] = 0.f;
    __syncthreads();

    const float4* W4 = (const float4*)W;

    const int n = blockIdx.x * NPB + (t >> 3);
    const int lane = t & 7;
    const bool active = (n < N);
    int gf_idx = (int)(blockIdx.x * NPB);
    if (gf_idx > N - 1) gf_idx = N - 1;
    const int gfirst = batch[gf_idx];

    float hacc[50];
#pragma unroll
    for (int j = 0; j < 50; ++j) hacc[j] = 0.f;

    uint s0 = 0, s1 = 0;
    float4 xr = make_float4(0.f, 0.f, 0.f, 0.f);
    int g = gfirst;
    if (active) {
        s0 = off[n]; s1 = off[n + 1];
        xr = xp[n];
        g = batch[n];
    }

    for (uint ia = s0 + lane; ia < s1; ia += GRP) {
        float4 da;
        if constexpr (PAYLOAD) {
            da = data[ia];
        } else {
            uint pa = perm[ia];
            int ca = ei[E + (int)pa];
            da = make_float4(ea[3*pa], ea[3*pa+1], ea[3*pa+2], __int_as_float(ca));
        }
        float4 xa = xp[__float_as_int(da.w)];

        float e2[15];
#pragma unroll
        for (int k = 0; k < 15; ++k) e2[k] = W[3195 + k];

        // edge MLP L1 (9->50, relu) fused with L2 (50->15)
#pragma unroll
        for (int j = 0; j < 50; ++j) {
            float4 wa = W4[j*3+0], wb = W4[j*3+1], wc = W4[j*3+2];
            float ta = fmaf(xr.x, wa.x, fmaf(xr.y, wa.y, fmaf(xr.z, wa.z, wc.y)));
            ta = fmaf(xa.x, wa.w, ta);
            ta = fmaf(xa.y, wb.x, ta); ta = fmaf(xa.z, wb.y, ta);
            ta = fmaf(da.x, wb.z, ta); ta = fmaf(da.y, wb.w, ta); ta = fmaf(da.z, wc.x, ta);
            ta = fmaxf(ta, 0.f);
            float4 u0 = W4[150 + j*4 + 0], u1 = W4[150 + j*4 + 1];
            float4 u2 = W4[150 + j*4 + 2], u3 = W4[150 + j*4 + 3];
            e2[0]  = fmaf(ta, u0.x, e2[0]);
            e2[1]  = fmaf(ta, u0.y, e2[1]);
            e2[2]  = fmaf(ta, u0.z, e2[2]);
            e2[3]  = fmaf(ta, u0.w, e2[3]);
            e2[4]  = fmaf(ta, u1.x, e2[4]);
            e2[5]  = fmaf(ta, u1.y, e2[5]);
            e2[6]  = fmaf(ta, u1.z, e2[6]);
            e2[7]  = fmaf(ta, u1.w, e2[7]);
            e2[8]  = fmaf(ta, u2.x, e2[8]);
            e2[9]  = fmaf(ta, u2.y, e2[9]);
            e2[10] = fmaf(ta, u2.z, e2[10]);
            e2[11] = fmaf(ta, u2.w, e2[11]);
            e2[12] = fmaf(ta, u3.x, e2[12]);
            e2[13] = fmaf(ta, u3.y, e2[13]);
            e2[14] = fmaf(ta, u3.z, e2[14]);
        }

        // node MLP L1 (18->50, relu), accumulate into hacc
#pragma unroll
        for (int j = 0; j < 50; ++j) {
            const int B = 350 + j * 5;
            float4 m0 = W4[B], m1 = W4[B+1], m2 = W4[B+2], m3 = W4[B+3], m4 = W4[B+4];
            float sa = m4.z;
            sa = fmaf(xa.x, m0.x, sa); sa = fmaf(xa.y, m0.y, sa); sa = fmaf(xa.z, m0.z, sa);
            sa = fmaf(e2[0],  m0.w, sa);
            sa = fmaf(e2[1],  m1.x, sa); sa = fmaf(e2[2],  m1.y, sa);
            sa = fmaf(e2[3],  m1.z, sa); sa = fmaf(e2[4],  m1.w, sa);
            sa = fmaf(e2[5],  m2.x, sa); sa = fmaf(e2[6],  m2.y, sa);
            sa = fmaf(e2[7],  m2.z, sa); sa = fmaf(e2[8],  m2.w, sa);
            sa = fmaf(e2[9],  m3.x, sa); sa = fmaf(e2[10], m3.y, sa);
            sa = fmaf(e2[11], m3.z, sa); sa = fmaf(e2[12], m3.w, sa);
            sa = fmaf(e2[13], m4.x, sa); sa = fmaf(e2[14], m4.y, sa);
            hacc[j] += fmaxf(sa, 0.f);
        }
    }

    // butterfly-reduce hacc over the 8 lanes of this node's group
#pragma unroll
    for (int m = 4; m > 0; m >>= 1)
#pragma unroll
        for (int j = 0; j < 50; ++j)
            hacc[j] += __shfl_xor(hacc[j], m);

    if (active) {
        float deg = (float)(s1 - s0);
        float inv = 1.f / fmaxf(deg, 1.f);
        int r = g - gfirst;                 // batch sorted -> usually 0..NPB
        bool local = (r <= NPB);            // guard: empty-graph gaps overflow gl
#pragma unroll
        for (int w = 0; w < 2; ++w) {
            int jj = lane + w * 8;
            if (jj < 15) {
                const float* rowp = &W[2400 + jj * 53];
                float acc = rowp[50] * deg;
#pragma unroll
                for (int i2 = 0; i2 < 50; ++i2) acc = fmaf(hacc[i2], rowp[i2], acc);
                if (local) atomicAdd(&gl[r][jj], acc * inv);
                else       atomicAdd(&g_acc[(size_t)g * 16 + jj], acc * inv);
            }
        }
        if (lane == 0) {
            if (local) atomicAdd(&gl[r][15], 1.f);
            else       atomicAdd(&g_acc[(size_t)g * 16 + 15], 1.f);
        }
    }
    __syncthreads();

    for (int idx = t; idx < (NPB + 1) * 16; idx += TPB) {
        int r = idx >> 4, c = idx & 15;
        if (gl[r][15] > 0.f)
            atomicAdd(&g_acc[(size_t)(gfirst + r) * 16 + c], gl[r][c]);
    }
}

// ---------------------------------------------------------------------------
// Global MLP + head (fc1 -> BN(batch stats) -> ReLU -> fc2 -> log_softmax)
// ---------------------------------------------------------------------------
__global__ __launch_bounds__(256) void global_head_kernel(
    const float* __restrict__ g_acc, const float* __restrict__ u,
    const float* __restrict__ gw1, const float* __restrict__ gb1,
    const float* __restrict__ gw2, const float* __restrict__ gb2,
    const float* __restrict__ f1w, const float* __restrict__ f1b,
    const float* __restrict__ bng, const float* __restrict__ bnb,
    const float* __restrict__ f2w, const float* __restrict__ f2b,
    float* __restrict__ out, int G)
{
    __shared__ float z[1024 * 10];
    __shared__ float red[2][10];

    float psum[10], psq[10];
#pragma unroll
    for (int j = 0; j < 10; ++j) { psum[j] = 0.f; psq[j] = 0.f; }

    for (int g = threadIdx.x; g < G; g += 256) {
        float gin[16];
        gin[0] = u[g];
        const float* src = g_acc + (size_t)g * 16;
        float inv = 1.f / fmaxf(src[15], 1.f);
#pragma unroll
        for (int j = 0; j < 15; ++j) gin[1 + j] = src[j] * inv;

        float h[50];
#pragma unroll
        for (int j = 0; j < 50; ++j) h[j] = gb1[j];
#pragma unroll
        for (int i = 0; i < 16; ++i) {
            float v = gin[i];
#pragma unroll
            for (int j = 0; j < 50; ++j) h[j] = fmaf(v, gw1[i*50+j], h[j]);
        }
#pragma unroll
        for (int j = 0; j < 50; ++j) h[j] = fmaxf(h[j], 0.f);

        float u2[15];
#pragma unroll
        for (int j = 0; j < 15; ++j) u2[j] = gb2[j];
#pragma unroll
        for (int i = 0; i < 50; ++i) {
            float v = h[i];
#pragma unroll
            for (int j = 0; j < 15; ++j) u2[j] = fmaf(v, gw2[i*15+j], u2[j]);
        }

#pragma unroll
        for (int j = 0; j < 10; ++j) {
            float acc = f1b[j];
#pragma unroll
            for (int i = 0; i < 15; ++i) acc = fmaf(u2[i], f1w[i*10+j], acc);
            z[g*10 + j] = acc;
            psum[j] += acc;
            psq[j]  += acc * acc;
        }
    }

    if (threadIdx.x == 0) {
#pragma unroll
        for (int j = 0; j < 10; ++j) { red[0][j] = 0.f; red[1][j] = 0.f; }
    }
    __syncthreads();
#pragma unroll
    for (int j = 0; j < 10; ++j) {
        atomicAdd(&red[0][j], psum[j]);
        atomicAdd(&red[1][j], psq[j]);
    }
    __syncthreads();

    float mean[10], rstd[10];
    float invG = 1.f / (float)G;
#pragma unroll
    for (int j = 0; j < 10; ++j) {
        mean[j] = red[0][j] * invG;
        float var = red[1][j] * invG - mean[j] * mean[j];
        rstd[j] = rsqrtf(var + 1e-5f);
    }

    for (int g = threadIdx.x; g < G; g += 256) {
        float l[6];
#pragma unroll
        for (int k = 0; k < 6; ++k) l[k] = f2b[k];
#pragma unroll
        for (int j = 0; j < 10; ++j) {
            float zn = (z[g*10 + j] - mean[j]) * rstd[j] * bng[j] + bnb[j];
            zn = fmaxf(zn, 0.f);
#pragma unroll
            for (int k = 0; k < 6; ++k) l[k] = fmaf(zn, f2w[j*6+k], l[k]);
        }
        float m = l[0];
#pragma unroll
        for (int k = 1; k < 6; ++k) m = fmaxf(m, l[k]);
        float s = 0.f;
#pragma unroll
        for (int k = 0; k < 6; ++k) s += expf(l[k] - m);
        float lse = m + logf(s);
#pragma unroll
        for (int k = 0; k < 6; ++k) out[g*6 + k] = l[k] - lse;
    }
}

extern "C" void kernel_launch(void* const* d_in, const int* in_sizes, int n_in,
                              void* d_out, int out_size, void* d_ws, size_t ws_size,
                              hipStream_t stream)
{
    const float* x   = (const float*)d_in[0];
    const int*   ei  = (const int*)d_in[1];
    const float* ea  = (const float*)d_in[2];
    const float* u   = (const float*)d_in[3];
    const int* batch = (const int*)d_in[4];
    const float* ew1 = (const float*)d_in[5];
    const float* eb1 = (const float*)d_in[6];
    const float* ew2 = (const float*)d_in[7];
    const float* eb2 = (const float*)d_in[8];
    const float* nw1 = (const float*)d_in[9];
    const float* nb1 = (const float*)d_in[10];
    const float* nw2 = (const float*)d_in[11];
    const float* nb2 = (const float*)d_in[12];
    const float* gw1 = (const float*)d_in[13];
    const float* gb1 = (const float*)d_in[14];
    const float* gw2 = (const float*)d_in[15];
    const float* gb2 = (const float*)d_in[16];
    const float* f1w = (const float*)d_in[17];
    const float* f1b = (const float*)d_in[18];
    const float* bng = (const float*)d_in[19];
    const float* bnb = (const float*)d_in[20];
    const float* f2w = (const float*)d_in[21];
    const float* f2b = (const float*)d_in[22];

    int N = in_sizes[0] / 3;
    int E = in_sizes[1] / 2;
    int G = in_sizes[3];
    int nb = (N + 1023) / 1024;

    // Plan A needs the full float4 payload array; plan B only perm indices.
    size_t fixed = (size_t)N * 16                      // xp
                 + ((size_t)3 * N + 1) * 4             // cnt, off, cur
                 + (size_t)nb * 8                      // bsum, boff
                 + (size_t)G * 64;                     // g_acc
    size_t needA = (size_t)E * 16 + fixed;
    bool planA = (ws_size >= needA);

    char* p = (char*)d_ws;
    float4* data = nullptr; uint* perm = nullptr;
    if (planA) { data = (float4*)p; p += (size_t)E * 16; }
    float4* xp = (float4*)p;            p += (size_t)N * 16;
    if (!planA) { perm = (uint*)p;      p += (size_t)E * 4; }
    uint* cnt  = (uint*)p;              p += (size_t)N * 4;
    uint* off  = (uint*)p;              p += ((size_t)N + 1) * 4;
    uint* cur  = (uint*)p;              p += (size_t)N * 4;
    uint* bsum = (uint*)p;              p += (size_t)nb * 4;
    uint* boff = (uint*)p;              p += (size_t)nb * 4;
    float* g_acc = (float*)p;

    (void)hipMemsetAsync(cnt, 0, sizeof(uint) * (size_t)N, stream);
    (void)hipMemsetAsync(g_acc, 0, sizeof(float) * (size_t)G * 16, stream);

    prep_kernel<<<(N + 255) / 256, 256, 0, stream>>>(x, xp, N);
    hist_kernel<<<(E + 255) / 256, 256, 0, stream>>>(ei, cnt, E);
    bsum_kernel<<<nb, 256, 0, stream>>>(cnt, bsum, N);
    scan_small_kernel<<<1, 1024, 0, stream>>>(bsum, boff, off, nb, N, E);
    scan_final_kernel<<<nb, 256, 0, stream>>>(cnt, boff, off, cur, N);

    if (planA) {
        scatter_payload_kernel<<<(E + 255) / 256, 256, 0, stream>>>(
            ei, ea, cur, data, E);
        node_kernel<true><<<(N + NPB - 1) / NPB, TPB, 0, stream>>>(
            xp, data, perm, ei, ea, off, batch,
            ew1, eb1, ew2, eb2, nw1, nb1, nw2, nb2, g_acc, N, E);
    } else {
        scatter_perm_kernel<<<(E + 255) / 256, 256, 0, stream>>>(
            ei, cur, perm, E);
        node_kernel<false><<<(N + NPB - 1) / NPB, TPB, 0, stream>>>(
            xp, data, perm, ei, ea, off, batch,
            ew1, eb1, ew2, eb2, nw1, nb1, nw2, nb2, g_acc, N, E);
    }

    global_head_kernel<<<1, 256, 0, stream>>>(
        g_acc, u, gw1, gb1, gw2, gb2, f1w, f1b, bng, bnb, f2w, f2b,
        (float*)d_out, G);
}

// Round 9
// 992.078 us; speedup vs baseline: 15.1693x; 15.1693x over previous
//
#include <hip/hip_runtime.h>

#define TPB 256
#define GRP 8
#define NPB (TPB / GRP)   // 32 nodes per block

typedef unsigned int uint;

// ---------------------------------------------------------------------------
// prep: pad x to float4 for single-load gathers
// ---------------------------------------------------------------------------
__global__ __launch_bounds__(256) void prep_kernel(
    const float* __restrict__ x, float4* __restrict__ xp, int N)
{
    int n = blockIdx.x * 256 + threadIdx.x;
    if (n < N) xp[n] = make_float4(x[3*n], x[3*n+1], x[3*n+2], 0.f);
}

// ---------------------------------------------------------------------------
// counting sort by row: hist -> (bsum, scan_small, scan_final) -> scatter
// ---------------------------------------------------------------------------
__global__ __launch_bounds__(256) void hist_kernel(
    const int* __restrict__ ei, uint* __restrict__ cnt, int E)
{
    int e = blockIdx.x * 256 + threadIdx.x;
    if (e < E) atomicAdd(&cnt[ei[e]], 1u);
}

__global__ __launch_bounds__(256) void bsum_kernel(
    const uint* __restrict__ cnt, uint* __restrict__ bsum, int N)
{
    __shared__ uint lds[256];
    int b = blockIdx.x, t = threadIdx.x;
    int base = b * 1024;
    uint s = 0;
    for (int k = 0; k < 4; ++k) {
        int i = base + t + k * 256;
        if (i < N) s += cnt[i];
    }
    lds[t] = s; __syncthreads();
    for (int st = 128; st > 0; st >>= 1) {
        if (t < st) lds[t] += lds[t + st];
        __syncthreads();
    }
    if (t == 0) bsum[b] = lds[0];
}

__global__ __launch_bounds__(1024) void scan_small_kernel(
    const uint* __restrict__ bsum, uint* __restrict__ boff,
    uint* __restrict__ off, int nb, int N, int E)
{
    __shared__ uint lds[1024];
    int t = threadIdx.x;
    uint v = (t < nb) ? bsum[t] : 0u;
    lds[t] = v; __syncthreads();
    for (int st = 1; st < 1024; st <<= 1) {
        uint u = (t >= st) ? lds[t - st] : 0u;
        __syncthreads();
        lds[t] += u; __syncthreads();
    }
    if (t < nb) boff[t] = lds[t] - v;
    if (t == 0) off[N] = (uint)E;
}

__global__ __launch_bounds__(256) void scan_final_kernel(
    const uint* __restrict__ cnt, const uint* __restrict__ boff,
    uint* __restrict__ off, uint* __restrict__ cur, int N)
{
    __shared__ uint lds[256];
    int b = blockIdx.x, t = threadIdx.x;
    int base = b * 1024;
    uint vals[4]; uint s = 0;
    for (int k = 0; k < 4; ++k) {
        int i = base + t * 4 + k;
        vals[k] = (i < N) ? cnt[i] : 0u;
        s += vals[k];
    }
    lds[t] = s; __syncthreads();
    for (int st = 1; st < 256; st <<= 1) {
        uint u = (t >= st) ? lds[t - st] : 0u;
        __syncthreads();
        lds[t] += u; __syncthreads();
    }
    uint run = boff[b] + lds[t] - s;
    for (int k = 0; k < 4; ++k) {
        int i = base + t * 4 + k;
        if (i < N) { off[i] = run; cur[i] = run; }
        run += vals[k];
    }
}

// Plan A: scatter full edge payload {ea0,ea1,ea2,col} into row-sorted position
__global__ __launch_bounds__(256) void scatter_payload_kernel(
    const int* __restrict__ ei, const float* __restrict__ ea,
    uint* __restrict__ cur, float4* __restrict__ data, int E)
{
    int e = blockIdx.x * 256 + threadIdx.x;
    if (e >= E) return;
    int r = ei[e], c = ei[E + e];
    uint p = atomicAdd(&cur[r], 1u);
    data[p] = make_float4(ea[3*e], ea[3*e+1], ea[3*e+2], __int_as_float(c));
}

// Plan B: scatter only the edge index (perm) — 4x less workspace
__global__ __launch_bounds__(256) void scatter_perm_kernel(
    const int* __restrict__ ei, uint* __restrict__ cur,
    uint* __restrict__ perm, int E)
{
    int e = blockIdx.x * 256 + threadIdx.x;
    if (e < E) {
        uint p = atomicAdd(&cur[ei[e]], 1u);
        perm[p] = (uint)e;
    }
}

// ---------------------------------------------------------------------------
// Node-centric fused MLP kernel. 8 lanes per node, one edge per lane per iter.
// Weights in LDS (broadcast ds_read_b128 at compile-time offsets).
// R6/R7 LESSON: with the j-loops fully unrolled, LLVM hoists the
// loop-invariant LDS weight loads across the whole body to hide DS latency,
// blowing VGPR to 256 and spilling (13-20 GB scratch traffic, 14 ms).
// Fix: sched_barrier(0) after every j-iteration bounds the live window to
// ~1 iteration of weights; __launch_bounds__(TPB,3) caps VGPR at ~168.
// Latency is hidden by TLP (12+ waves/CU), not by cross-iteration ILP.
// W layout (floats): EW1T[50][12]@0 (w0..w8,b,pad2) | EW2P[50][16]@600
//   (15w,pad) | NW1T[50][20]@1400 (3xc,15e2,b,pad) | NW2T[15][53]@2400
//   (50w,b,pad2) | EB2[15]@3195
// ---------------------------------------------------------------------------
template<bool PAYLOAD>
__global__ __launch_bounds__(TPB, 3) void node_kernel(
    const float4* __restrict__ xp, const float4* __restrict__ data,
    const uint* __restrict__ perm,
    const int* __restrict__ ei, const float* __restrict__ ea,
    const uint* __restrict__ off, const int* __restrict__ batch,
    const float* __restrict__ ew1, const float* __restrict__ eb1,
    const float* __restrict__ ew2, const float* __restrict__ eb2,
    const float* __restrict__ nw1, const float* __restrict__ nb1,
    const float* __restrict__ nw2, const float* __restrict__ nb2,
    float* __restrict__ g_acc, int N, int E)
{
    __shared__ float W[3216];
    __shared__ float gl[NPB + 1][16];
    const int t = threadIdx.x;

    for (int idx = t; idx < 600; idx += TPB) {            // EW1T
        int j = idx / 12, p = idx - j * 12;
        float v = 0.f;
        if (p < 9) v = ew1[p * 50 + j];
        else if (p == 9) v = eb1[j];
        W[idx] = v;
    }
    for (int idx = t; idx < 800; idx += TPB) {            // EW2P
        int j = idx / 16, k = idx - j * 16;
        W[600 + idx] = (k < 15) ? ew2[j * 15 + k] : 0.f;
    }
    for (int idx = t; idx < 1000; idx += TPB) {           // NW1T
        int j = idx / 20, p = idx - j * 20;
        float v = 0.f;
        if (p < 18) v = nw1[p * 50 + j];
        else if (p == 18) v = nb1[j];
        W[1400 + idx] = v;
    }
    for (int idx = t; idx < 795; idx += TPB) {            // NW2T
        int jj = idx / 53, p = idx - jj * 53;
        float v = 0.f;
        if (p < 50) v = nw2[p * 15 + jj];
        else if (p == 50) v = nb2[jj];
        W[2400 + idx] = v;
    }
    if (t < 15) W[3195 + t] = eb2[t];
    for (int idx = t; idx < (NPB + 1) * 16; idx += TPB)
        ((float*)gl)[idx] = 0.f;
    __syncthreads();

    const float4* W4 = (const float4*)W;

    const int n = blockIdx.x * NPB + (t >> 3);
    const int lane = t & 7;
    const bool active = (n < N);
    int gf_idx = (int)(blockIdx.x * NPB);
    if (gf_idx > N - 1) gf_idx = N - 1;
    const int gfirst = batch[gf_idx];

    float hacc[50];
#pragma unroll
    for (int j = 0; j < 50; ++j) hacc[j] = 0.f;

    uint s0 = 0, s1 = 0;
    float4 xr = make_float4(0.f, 0.f, 0.f, 0.f);
    int g = gfirst;
    if (active) {
        s0 = off[n]; s1 = off[n + 1];
        xr = xp[n];
        g = batch[n];
    }

    for (uint ia = s0 + lane; ia < s1; ia += GRP) {
        float4 da;
        if constexpr (PAYLOAD) {
            da = data[ia];
        } else {
            uint pa = perm[ia];
            int ca = ei[E + (int)pa];
            da = make_float4(ea[3*pa], ea[3*pa+1], ea[3*pa+2], __int_as_float(ca));
        }
        float4 xa = xp[__float_as_int(da.w)];

        float e2[15];
#pragma unroll
        for (int k = 0; k < 15; ++k) e2[k] = W[3195 + k];

        // edge MLP L1 (9->50, relu) fused with L2 (50->15)
#pragma unroll
        for (int j = 0; j < 50; ++j) {
            float4 wa = W4[j*3+0], wb = W4[j*3+1], wc = W4[j*3+2];
            float ta = fmaf(xr.x, wa.x, fmaf(xr.y, wa.y, fmaf(xr.z, wa.z, wc.y)));
            ta = fmaf(xa.x, wa.w, ta);
            ta = fmaf(xa.y, wb.x, ta); ta = fmaf(xa.z, wb.y, ta);
            ta = fmaf(da.x, wb.z, ta); ta = fmaf(da.y, wb.w, ta); ta = fmaf(da.z, wc.x, ta);
            ta = fmaxf(ta, 0.f);
            float4 u0 = W4[150 + j*4 + 0], u1 = W4[150 + j*4 + 1];
            float4 u2 = W4[150 + j*4 + 2], u3 = W4[150 + j*4 + 3];
            e2[0]  = fmaf(ta, u0.x, e2[0]);
            e2[1]  = fmaf(ta, u0.y, e2[1]);
            e2[2]  = fmaf(ta, u0.z, e2[2]);
            e2[3]  = fmaf(ta, u0.w, e2[3]);
            e2[4]  = fmaf(ta, u1.x, e2[4]);
            e2[5]  = fmaf(ta, u1.y, e2[5]);
            e2[6]  = fmaf(ta, u1.z, e2[6]);
            e2[7]  = fmaf(ta, u1.w, e2[7]);
            e2[8]  = fmaf(ta, u2.x, e2[8]);
            e2[9]  = fmaf(ta, u2.y, e2[9]);
            e2[10] = fmaf(ta, u2.z, e2[10]);
            e2[11] = fmaf(ta, u2.w, e2[11]);
            e2[12] = fmaf(ta, u3.x, e2[12]);
            e2[13] = fmaf(ta, u3.y, e2[13]);
            e2[14] = fmaf(ta, u3.z, e2[14]);
            __builtin_amdgcn_sched_barrier(0);   // cap LDS-load hoisting window
        }

        // node MLP L1 (18->50, relu), accumulate into hacc
#pragma unroll
        for (int j = 0; j < 50; ++j) {
            const int B = 350 + j * 5;
            float4 m0 = W4[B], m1 = W4[B+1], m2 = W4[B+2], m3 = W4[B+3], m4 = W4[B+4];
            float sa = m4.z;
            sa = fmaf(xa.x, m0.x, sa); sa = fmaf(xa.y, m0.y, sa); sa = fmaf(xa.z, m0.z, sa);
            sa = fmaf(e2[0],  m0.w, sa);
            sa = fmaf(e2[1],  m1.x, sa); sa = fmaf(e2[2],  m1.y, sa);
            sa = fmaf(e2[3],  m1.z, sa); sa = fmaf(e2[4],  m1.w, sa);
            sa = fmaf(e2[5],  m2.x, sa); sa = fmaf(e2[6],  m2.y, sa);
            sa = fmaf(e2[7],  m2.z, sa); sa = fmaf(e2[8],  m2.w, sa);
            sa = fmaf(e2[9],  m3.x, sa); sa = fmaf(e2[10], m3.y, sa);
            sa = fmaf(e2[11], m3.z, sa); sa = fmaf(e2[12], m3.w, sa);
            sa = fmaf(e2[13], m4.x, sa); sa = fmaf(e2[14], m4.y, sa);
            hacc[j] += fmaxf(sa, 0.f);
            __builtin_amdgcn_sched_barrier(0);   // cap LDS-load hoisting window
        }
    }

    // butterfly-reduce hacc over the 8 lanes of this node's group
#pragma unroll
    for (int m = 4; m > 0; m >>= 1)
#pragma unroll
        for (int j = 0; j < 50; ++j)
            hacc[j] += __shfl_xor(hacc[j], m);

    if (active) {
        float deg = (float)(s1 - s0);
        float inv = 1.f / fmaxf(deg, 1.f);
        int r = g - gfirst;                 // batch sorted -> usually 0..NPB
        bool local = (r <= NPB);            // guard: empty-graph gaps overflow gl
#pragma unroll
        for (int w = 0; w < 2; ++w) {
            int jj = lane + w * 8;
            if (jj < 15) {
                const float* rowp = &W[2400 + jj * 53];
                float acc = rowp[50] * deg;
#pragma unroll
                for (int i2 = 0; i2 < 50; ++i2) acc = fmaf(hacc[i2], rowp[i2], acc);
                if (local) atomicAdd(&gl[r][jj], acc * inv);
                else       atomicAdd(&g_acc[(size_t)g * 16 + jj], acc * inv);
            }
        }
        if (lane == 0) {
            if (local) atomicAdd(&gl[r][15], 1.f);
            else       atomicAdd(&g_acc[(size_t)g * 16 + 15], 1.f);
        }
    }
    __syncthreads();

    for (int idx = t; idx < (NPB + 1) * 16; idx += TPB) {
        int r = idx >> 4, c = idx & 15;
        if (gl[r][15] > 0.f)
            atomicAdd(&g_acc[(size_t)(gfirst + r) * 16 + c], gl[r][c]);
    }
}

// ---------------------------------------------------------------------------
// Global MLP + head (fc1 -> BN(batch stats) -> ReLU -> fc2 -> log_softmax)
// ---------------------------------------------------------------------------
__global__ __launch_bounds__(256) void global_head_kernel(
    const float* __restrict__ g_acc, const float* __restrict__ u,
    const float* __restrict__ gw1, const float* __restrict__ gb1,
    const float* __restrict__ gw2, const float* __restrict__ gb2,
    const float* __restrict__ f1w, const float* __restrict__ f1b,
    const float* __restrict__ bng, const float* __restrict__ bnb,
    const float* __restrict__ f2w, const float* __restrict__ f2b,
    float* __restrict__ out, int G)
{
    __shared__ float z[1024 * 10];
    __shared__ float red[2][10];

    float psum[10], psq[10];
#pragma unroll
    for (int j = 0; j < 10; ++j) { psum[j] = 0.f; psq[j] = 0.f; }

    for (int g = threadIdx.x; g < G; g += 256) {
        float gin[16];
        gin[0] = u[g];
        const float* src = g_acc + (size_t)g * 16;
        float inv = 1.f / fmaxf(src[15], 1.f);
#pragma unroll
        for (int j = 0; j < 15; ++j) gin[1 + j] = src[j] * inv;

        float h[50];
#pragma unroll
        for (int j = 0; j < 50; ++j) h[j] = gb1[j];
#pragma unroll
        for (int i = 0; i < 16; ++i) {
            float v = gin[i];
#pragma unroll
            for (int j = 0; j < 50; ++j) h[j] = fmaf(v, gw1[i*50+j], h[j]);
        }
#pragma unroll
        for (int j = 0; j < 50; ++j) h[j] = fmaxf(h[j], 0.f);

        float u2[15];
#pragma unroll
        for (int j = 0; j < 15; ++j) u2[j] = gb2[j];
#pragma unroll
        for (int i = 0; i < 50; ++i) {
            float v = h[i];
#pragma unroll
            for (int j = 0; j < 15; ++j) u2[j] = fmaf(v, gw2[i*15+j], u2[j]);
        }

#pragma unroll
        for (int j = 0; j < 10; ++j) {
            float acc = f1b[j];
#pragma unroll
            for (int i = 0; i < 15; ++i) acc = fmaf(u2[i], f1w[i*10+j], acc);
            z[g*10 + j] = acc;
            psum[j] += acc;
            psq[j]  += acc * acc;
        }
    }

    if (threadIdx.x == 0) {
#pragma unroll
        for (int j = 0; j < 10; ++j) { red[0][j] = 0.f; red[1][j] = 0.f; }
    }
    __syncthreads();
#pragma unroll
    for (int j = 0; j < 10; ++j) {
        atomicAdd(&red[0][j], psum[j]);
        atomicAdd(&red[1][j], psq[j]);
    }
    __syncthreads();

    float mean[10], rstd[10];
    float invG = 1.f / (float)G;
#pragma unroll
    for (int j = 0; j < 10; ++j) {
        mean[j] = red[0][j] * invG;
        float var = red[1][j] * invG - mean[j] * mean[j];
        rstd[j] = rsqrtf(var + 1e-5f);
    }

    for (int g = threadIdx.x; g < G; g += 256) {
        float l[6];
#pragma unroll
        for (int k = 0; k < 6; ++k) l[k] = f2b[k];
#pragma unroll
        for (int j = 0; j < 10; ++j) {
            float zn = (z[g*10 + j] - mean[j]) * rstd[j] * bng[j] + bnb[j];
            zn = fmaxf(zn, 0.f);
#pragma unroll
            for (int k = 0; k < 6; ++k) l[k] = fmaf(zn, f2w[j*6+k], l[k]);
        }
        float m = l[0];
#pragma unroll
        for (int k = 1; k < 6; ++k) m = fmaxf(m, l[k]);
        float s = 0.f;
#pragma unroll
        for (int k = 0; k < 6; ++k) s += expf(l[k] - m);
        float lse = m + logf(s);
#pragma unroll
        for (int k = 0; k < 6; ++k) out[g*6 + k] = l[k] - lse;
    }
}

extern "C" void kernel_launch(void* const* d_in, const int* in_sizes, int n_in,
                              void* d_out, int out_size, void* d_ws, size_t ws_size,
                              hipStream_t stream)
{
    const float* x   = (const float*)d_in[0];
    const int*   ei  = (const int*)d_in[1];
    const float* ea  = (const float*)d_in[2];
    const float* u   = (const float*)d_in[3];
    const int* batch = (const int*)d_in[4];
    const float* ew1 = (const float*)d_in[5];
    const float* eb1 = (const float*)d_in[6];
    const float* ew2 = (const float*)d_in[7];
    const float* eb2 = (const float*)d_in[8];
    const float* nw1 = (const float*)d_in[9];
    const float* nb1 = (const float*)d_in[10];
    const float* nw2 = (const float*)d_in[11];
    const float* nb2 = (const float*)d_in[12];
    const float* gw1 = (const float*)d_in[13];
    const float* gb1 = (const float*)d_in[14];
    const float* gw2 = (const float*)d_in[15];
    const float* gb2 = (const float*)d_in[16];
    const float* f1w = (const float*)d_in[17];
    const float* f1b = (const float*)d_in[18];
    const float* bng = (const float*)d_in[19];
    const float* bnb = (const float*)d_in[20];
    const float* f2w = (const float*)d_in[21];
    const float* f2b = (const float*)d_in[22];

    int N = in_sizes[0] / 3;
    int E = in_sizes[1] / 2;
    int G = in_sizes[3];
    int nb = (N + 1023) / 1024;

    // Plan A needs the full float4 payload array; plan B only perm indices.
    size_t fixed = (size_t)N * 16                      // xp
                 + ((size_t)3 * N + 1) * 4             // cnt, off, cur
                 + (size_t)nb * 8                      // bsum, boff
                 + (size_t)G * 64;                     // g_acc
    size_t needA = (size_t)E * 16 + fixed;
    bool planA = (ws_size >= needA);

    char* p = (char*)d_ws;
    float4* data = nullptr; uint* perm = nullptr;
    if (planA) { data = (float4*)p; p += (size_t)E * 16; }
    float4* xp = (float4*)p;            p += (size_t)N * 16;
    if (!planA) { perm = (uint*)p;      p += (size_t)E * 4; }
    uint* cnt  = (uint*)p;              p += (size_t)N * 4;
    uint* off  = (uint*)p;              p += ((size_t)N + 1) * 4;
    uint* cur  = (uint*)p;              p += (size_t)N * 4;
    uint* bsum = (uint*)p;              p += (size_t)nb * 4;
    uint* boff = (uint*)p;              p += (size_t)nb * 4;
    float* g_acc = (float*)p;

    (void)hipMemsetAsync(cnt, 0, sizeof(uint) * (size_t)N, stream);
    (void)hipMemsetAsync(g_acc, 0, sizeof(float) * (size_t)G * 16, stream);

    prep_kernel<<<(N + 255) / 256, 256, 0, stream>>>(x, xp, N);
    hist_kernel<<<(E + 255) / 256, 256, 0, stream>>>(ei, cnt, E);
    bsum_kernel<<<nb, 256, 0, stream>>>(cnt, bsum, N);
    scan_small_kernel<<<1, 1024, 0, stream>>>(bsum, boff, off, nb, N, E);
    scan_final_kernel<<<nb, 256, 0, stream>>>(cnt, boff, off, cur, N);

    if (planA) {
        scatter_payload_kernel<<<(E + 255) / 256, 256, 0, stream>>>(
            ei, ea, cur, data, E);
        node_kernel<true><<<(N + NPB - 1) / NPB, TPB, 0, stream>>>(
            xp, data, perm, ei, ea, off, batch,
            ew1, eb1, ew2, eb2, nw1, nb1, nw2, nb2, g_acc, N, E);
    } else {
        scatter_perm_kernel<<<(E + 255) / 256, 256, 0, stream>>>(
            ei, cur, perm, E);
        node_kernel<false><<<(N + NPB - 1) / NPB, TPB, 0, stream>>>(
            xp, data, perm, ei, ea, off, batch,
            ew1, eb1, ew2, eb2, nw1, nb1, nw2, nb2, g_acc, N, E);
    }

    global_head_kernel<<<1, 256, 0, stream>>>(
        g_acc, u, gw1, gb1, gw2, gb2, f1w, f1b, bng, bnb, f2w, f2b,
        (float*)d_out, G);
}

// Round 11
// 903.923 us; speedup vs baseline: 16.6487x; 1.0975x over previous
//
#include <hip/hip_runtime.h>

#define TPB 256
#define GRP 8
#define NPB (TPB / GRP)   // 32 nodes per block

typedef unsigned int uint;

// ---------------------------------------------------------------------------
// prep: pad x to float4 for single-load gathers
// ---------------------------------------------------------------------------
__global__ __launch_bounds__(256) void prep_kernel(
    const float* __restrict__ x, float4* __restrict__ xp, int N)
{
    int n = blockIdx.x * 256 + threadIdx.x;
    if (n < N) xp[n] = make_float4(x[3*n], x[3*n+1], x[3*n+2], 0.f);
}

// ---------------------------------------------------------------------------
// counting sort by row: hist -> (bsum, scan_small, scan_final) -> scatter
// ---------------------------------------------------------------------------
__global__ __launch_bounds__(256) void hist_kernel(
    const int* __restrict__ ei, uint* __restrict__ cnt, int E)
{
    int e = blockIdx.x * 256 + threadIdx.x;
    if (e < E) atomicAdd(&cnt[ei[e]], 1u);
}

__global__ __launch_bounds__(256) void bsum_kernel(
    const uint* __restrict__ cnt, uint* __restrict__ bsum, int N)
{
    __shared__ uint lds[256];
    int b = blockIdx.x, t = threadIdx.x;
    int base = b * 1024;
    uint s = 0;
    for (int k = 0; k < 4; ++k) {
        int i = base + t + k * 256;
        if (i < N) s += cnt[i];
    }
    lds[t] = s; __syncthreads();
    for (int st = 128; st > 0; st >>= 1) {
        if (t < st) lds[t] += lds[t + st];
        __syncthreads();
    }
    if (t == 0) bsum[b] = lds[0];
}

__global__ __launch_bounds__(1024) void scan_small_kernel(
    const uint* __restrict__ bsum, uint* __restrict__ boff,
    uint* __restrict__ off, int nb, int N, int E)
{
    __shared__ uint lds[1024];
    int t = threadIdx.x;
    uint v = (t < nb) ? bsum[t] : 0u;
    lds[t] = v; __syncthreads();
    for (int st = 1; st < 1024; st <<= 1) {
        uint u = (t >= st) ? lds[t - st] : 0u;
        __syncthreads();
        lds[t] += u; __syncthreads();
    }
    if (t < nb) boff[t] = lds[t] - v;
    if (t == 0) off[N] = (uint)E;
}

__global__ __launch_bounds__(256) void scan_final_kernel(
    const uint* __restrict__ cnt, const uint* __restrict__ boff,
    uint* __restrict__ off, uint* __restrict__ cur, int N)
{
    __shared__ uint lds[256];
    int b = blockIdx.x, t = threadIdx.x;
    int base = b * 1024;
    uint vals[4]; uint s = 0;
    for (int k = 0; k < 4; ++k) {
        int i = base + t * 4 + k;
        vals[k] = (i < N) ? cnt[i] : 0u;
        s += vals[k];
    }
    lds[t] = s; __syncthreads();
    for (int st = 1; st < 256; st <<= 1) {
        uint u = (t >= st) ? lds[t - st] : 0u;
        __syncthreads();
        lds[t] += u; __syncthreads();
    }
    uint run = boff[b] + lds[t] - s;
    for (int k = 0; k < 4; ++k) {
        int i = base + t * 4 + k;
        if (i < N) { off[i] = run; cur[i] = run; }
        run += vals[k];
    }
}

// Plan A: scatter full edge payload {ea0,ea1,ea2,col} into row-sorted position
__global__ __launch_bounds__(256) void scatter_payload_kernel(
    const int* __restrict__ ei, const float* __restrict__ ea,
    uint* __restrict__ cur, float4* __restrict__ data, int E)
{
    int e = blockIdx.x * 256 + threadIdx.x;
    if (e >= E) return;
    int r = ei[e], c = ei[E + e];
    uint p = atomicAdd(&cur[r], 1u);
    data[p] = make_float4(ea[3*e], ea[3*e+1], ea[3*e+2], __int_as_float(c));
}

// Plan B: scatter only the edge index (perm) — 4x less workspace
__global__ __launch_bounds__(256) void scatter_perm_kernel(
    const int* __restrict__ ei, uint* __restrict__ cur,
    uint* __restrict__ perm, int E)
{
    int e = blockIdx.x * 256 + threadIdx.x;
    if (e < E) {
        uint p = atomicAdd(&cur[ei[e]], 1u);
        perm[p] = (uint)e;
    }
}

// ---------------------------------------------------------------------------
// Node-centric fused MLP kernel. 8 lanes per node, TWO edges per lane per
// iteration sharing one set of weight reads (R9 showed the kernel is
// LDS-issue-bound: 600 broadcast ds_read_b128 per 64-edge wave vs ~2350
// VALU; per-CU DS pipe shared by 4 SIMDs is the critical resource).
// 2-edge blocking halves DS instrs per edge. Spill protection (from R9,
// which fixed R6/R7's 256-VGPR 14ms spill): sched_barrier(0) after every
// j-iteration bounds LLVM's LDS-load hoisting window; __launch_bounds__
// (TPB,3) caps VGPR ~168. Live set ~132 regs.
// W layout (floats): EW1T[50][12]@0 (w0..w8,b,pad2) | EW2P[50][16]@600
//   (15w,pad) | NW1T[50][20]@1400 (3xc,15e2,b,pad) | NW2T[15][53]@2400
//   (50w,b,pad2) | EB2[15]@3195
// ---------------------------------------------------------------------------
template<bool PAYLOAD>
__global__ __launch_bounds__(TPB, 3) void node_kernel(
    const float4* __restrict__ xp, const float4* __restrict__ data,
    const uint* __restrict__ perm,
    const int* __restrict__ ei, const float* __restrict__ ea,
    const uint* __restrict__ off, const int* __restrict__ batch,
    const float* __restrict__ ew1, const float* __restrict__ eb1,
    const float* __restrict__ ew2, const float* __restrict__ eb2,
    const float* __restrict__ nw1, const float* __restrict__ nb1,
    const float* __restrict__ nw2, const float* __restrict__ nb2,
    float* __restrict__ g_acc, int N, int E)
{
    __shared__ float W[3216];
    __shared__ float gl[NPB + 1][16];
    const int t = threadIdx.x;

    for (int idx = t; idx < 600; idx += TPB) {            // EW1T
        int j = idx / 12, p = idx - j * 12;
        float v = 0.f;
        if (p < 9) v = ew1[p * 50 + j];
        else if (p == 9) v = eb1[j];
        W[idx] = v;
    }
    for (int idx = t; idx < 800; idx += TPB) {            // EW2P
        int j = idx / 16, k = idx - j * 16;
        W[600 + idx] = (k < 15) ? ew2[j * 15 + k] : 0.f;
    }
    for (int idx = t; idx < 1000; idx += TPB) {           // NW1T
        int j = idx / 20, p = idx - j * 20;
        float v = 0.f;
        if (p < 18) v = nw1[p * 50 + j];
        else if (p == 18) v = nb1[j];
        W[1400 + idx] = v;
    }
    for (int idx = t; idx < 795; idx += TPB) {            // NW2T
        int jj = idx / 53, p = idx - jj * 53;
        float v = 0.f;
        if (p < 50) v = nw2[p * 15 + jj];
        else if (p == 50) v = nb2[jj];
        W[2400 + idx] = v;
    }
    if (t < 15) W[3195 + t] = eb2[t];
    for (int idx = t; idx < (NPB + 1) * 16; idx += TPB)
        ((float*)gl)[idx] = 0.f;
    __syncthreads();

    const float4* W4 = (const float4*)W;

    const int n = blockIdx.x * NPB + (t >> 3);
    const int lane = t & 7;
    const bool active = (n < N);
    int gf_idx = (int)(blockIdx.x * NPB);
    if (gf_idx > N - 1) gf_idx = N - 1;
    const int gfirst = batch[gf_idx];

    float hacc[50];
#pragma unroll
    for (int j = 0; j < 50; ++j) hacc[j] = 0.f;

    uint s0 = 0, s1 = 0;
    float4 xr = make_float4(0.f, 0.f, 0.f, 0.f);
    int g = gfirst;
    if (active) {
        s0 = off[n]; s1 = off[n + 1];
        xr = xp[n];
        g = batch[n];
    }

    for (uint ia = s0 + lane; ia < s1; ia += 2 * GRP) {
        uint ibr = ia + GRP;
        float vb = (ibr < s1) ? 1.f : 0.f;
        uint ib = ibr < (uint)(E - 1) ? ibr : (uint)(E - 1);

        float4 da, db;
        if constexpr (PAYLOAD) {
            da = data[ia]; db = data[ib];
        } else {
            uint pa = perm[ia], pb = perm[ib];
            int ca = ei[E + (int)pa], cb = ei[E + (int)pb];
            da = make_float4(ea[3*pa], ea[3*pa+1], ea[3*pa+2], __int_as_float(ca));
            db = make_float4(ea[3*pb], ea[3*pb+1], ea[3*pb+2], __int_as_float(cb));
        }
        float4 xa = xp[__float_as_int(da.w)];
        float4 xb = xp[__float_as_int(db.w)];

        float e2a[15], e2b[15];
#pragma unroll
        for (int k = 0; k < 15; ++k) { float bk = W[3195 + k]; e2a[k] = bk; e2b[k] = bk; }

        // edge MLP L1 (9->50, relu) fused with L2 (50->15), 2 edges / weight read
#pragma unroll
        for (int j = 0; j < 50; ++j) {
            float4 wa = W4[j*3+0], wb = W4[j*3+1], wc = W4[j*3+2];
            float base = fmaf(xr.x, wa.x, fmaf(xr.y, wa.y, fmaf(xr.z, wa.z, wc.y)));
            float ta = fmaf(xa.x, wa.w, base);
            ta = fmaf(xa.y, wb.x, ta); ta = fmaf(xa.z, wb.y, ta);
            ta = fmaf(da.x, wb.z, ta); ta = fmaf(da.y, wb.w, ta); ta = fmaf(da.z, wc.x, ta);
            float tb = fmaf(xb.x, wa.w, base);
            tb = fmaf(xb.y, wb.x, tb); tb = fmaf(xb.z, wb.y, tb);
            tb = fmaf(db.x, wb.z, tb); tb = fmaf(db.y, wb.w, tb); tb = fmaf(db.z, wc.x, tb);
            ta = fmaxf(ta, 0.f); tb = fmaxf(tb, 0.f);
            float4 u0 = W4[150 + j*4 + 0], u1 = W4[150 + j*4 + 1];
            float4 u2 = W4[150 + j*4 + 2], u3 = W4[150 + j*4 + 3];
            e2a[0]  = fmaf(ta, u0.x, e2a[0]);  e2b[0]  = fmaf(tb, u0.x, e2b[0]);
            e2a[1]  = fmaf(ta, u0.y, e2a[1]);  e2b[1]  = fmaf(tb, u0.y, e2b[1]);
            e2a[2]  = fmaf(ta, u0.z, e2a[2]);  e2b[2]  = fmaf(tb, u0.z, e2b[2]);
            e2a[3]  = fmaf(ta, u0.w, e2a[3]);  e2b[3]  = fmaf(tb, u0.w, e2b[3]);
            e2a[4]  = fmaf(ta, u1.x, e2a[4]);  e2b[4]  = fmaf(tb, u1.x, e2b[4]);
            e2a[5]  = fmaf(ta, u1.y, e2a[5]);  e2b[5]  = fmaf(tb, u1.y, e2b[5]);
            e2a[6]  = fmaf(ta, u1.z, e2a[6]);  e2b[6]  = fmaf(tb, u1.z, e2b[6]);
            e2a[7]  = fmaf(ta, u1.w, e2a[7]);  e2b[7]  = fmaf(tb, u1.w, e2b[7]);
            e2a[8]  = fmaf(ta, u2.x, e2a[8]);  e2b[8]  = fmaf(tb, u2.x, e2b[8]);
            e2a[9]  = fmaf(ta, u2.y, e2a[9]);  e2b[9]  = fmaf(tb, u2.y, e2b[9]);
            e2a[10] = fmaf(ta, u2.z, e2a[10]); e2b[10] = fmaf(tb, u2.z, e2b[10]);
            e2a[11] = fmaf(ta, u2.w, e2a[11]); e2b[11] = fmaf(tb, u2.w, e2b[11]);
            e2a[12] = fmaf(ta, u3.x, e2a[12]); e2b[12] = fmaf(tb, u3.x, e2b[12]);
            e2a[13] = fmaf(ta, u3.y, e2a[13]); e2b[13] = fmaf(tb, u3.y, e2b[13]);
            e2a[14] = fmaf(ta, u3.z, e2a[14]); e2b[14] = fmaf(tb, u3.z, e2b[14]);
            __builtin_amdgcn_sched_barrier(0);   // cap LDS-load hoisting window
        }

        // node MLP L1 (18->50, relu), accumulate into hacc, 2 edges / read
#pragma unroll
        for (int j = 0; j < 50; ++j) {
            const int B = 350 + j * 5;
            float4 m0 = W4[B], m1 = W4[B+1], m2 = W4[B+2], m3 = W4[B+3], m4 = W4[B+4];
            float sa = m4.z;
            sa = fmaf(xa.x, m0.x, sa); sa = fmaf(xa.y, m0.y, sa); sa = fmaf(xa.z, m0.z, sa);
            sa = fmaf(e2a[0],  m0.w, sa);
            sa = fmaf(e2a[1],  m1.x, sa); sa = fmaf(e2a[2],  m1.y, sa);
            sa = fmaf(e2a[3],  m1.z, sa); sa = fmaf(e2a[4],  m1.w, sa);
            sa = fmaf(e2a[5],  m2.x, sa); sa = fmaf(e2a[6],  m2.y, sa);
            sa = fmaf(e2a[7],  m2.z, sa); sa = fmaf(e2a[8],  m2.w, sa);
            sa = fmaf(e2a[9],  m3.x, sa); sa = fmaf(e2a[10], m3.y, sa);
            sa = fmaf(e2a[11], m3.z, sa); sa = fmaf(e2a[12], m3.w, sa);
            sa = fmaf(e2a[13], m4.x, sa); sa = fmaf(e2a[14], m4.y, sa);
            float sb = m4.z;
            sb = fmaf(xb.x, m0.x, sb); sb = fmaf(xb.y, m0.y, sb); sb = fmaf(xb.z, m0.z, sb);
            sb = fmaf(e2b[0],  m0.w, sb);
            sb = fmaf(e2b[1],  m1.x, sb); sb = fmaf(e2b[2],  m1.y, sb);
            sb = fmaf(e2b[3],  m1.z, sb); sb = fmaf(e2b[4],  m1.w, sb);
            sb = fmaf(e2b[5],  m2.x, sb); sb = fmaf(e2b[6],  m2.y, sb);
            sb = fmaf(e2b[7],  m2.z, sb); sb = fmaf(e2b[8],  m2.w, sb);
            sb = fmaf(e2b[9],  m3.x, sb); sb = fmaf(e2b[10], m3.y, sb);
            sb = fmaf(e2b[11], m3.z, sb); sb = fmaf(e2b[12], m3.w, sb);
            sb = fmaf(e2b[13], m4.x, sb); sb = fmaf(e2b[14], m4.y, sb);
            hacc[j] += fmaxf(sa, 0.f);
            hacc[j] = fmaf(vb, fmaxf(sb, 0.f), hacc[j]);
            __builtin_amdgcn_sched_barrier(0);   // cap LDS-load hoisting window
        }
    }

    // butterfly-reduce hacc over the 8 lanes of this node's group
#pragma unroll
    for (int m = 4; m > 0; m >>= 1)
#pragma unroll
        for (int j = 0; j < 50; ++j)
            hacc[j] += __shfl_xor(hacc[j], m);

    if (active) {
        float deg = (float)(s1 - s0);
        float inv = 1.f / fmaxf(deg, 1.f);
        int r = g - gfirst;                 // batch sorted -> usually 0..NPB
        bool local = (r <= NPB);            // guard: empty-graph gaps overflow gl
#pragma unroll
        for (int w = 0; w < 2; ++w) {
            int jj = lane + w * 8;
            if (jj < 15) {
                const float* rowp = &W[2400 + jj * 53];
                float acc = rowp[50] * deg;
#pragma unroll
                for (int i2 = 0; i2 < 50; ++i2) acc = fmaf(hacc[i2], rowp[i2], acc);
                if (local) atomicAdd(&gl[r][jj], acc * inv);
                else       atomicAdd(&g_acc[(size_t)g * 16 + jj], acc * inv);
            }
        }
        if (lane == 0) {
            if (local) atomicAdd(&gl[r][15], 1.f);
            else       atomicAdd(&g_acc[(size_t)g * 16 + 15], 1.f);
        }
    }
    __syncthreads();

    for (int idx = t; idx < (NPB + 1) * 16; idx += TPB) {
        int r = idx >> 4, c = idx & 15;
        if (gl[r][15] > 0.f)
            atomicAdd(&g_acc[(size_t)(gfirst + r) * 16 + c], gl[r][c]);
    }
}

// ---------------------------------------------------------------------------
// Global MLP + head (fc1 -> BN(batch stats) -> ReLU -> fc2 -> log_softmax)
// ---------------------------------------------------------------------------
__global__ __launch_bounds__(256) void global_head_kernel(
    const float* __restrict__ g_acc, const float* __restrict__ u,
    const float* __restrict__ gw1, const float* __restrict__ gb1,
    const float* __restrict__ gw2, const float* __restrict__ gb2,
    const float* __restrict__ f1w, const float* __restrict__ f1b,
    const float* __restrict__ bng, const float* __restrict__ bnb,
    const float* __restrict__ f2w, const float* __restrict__ f2b,
    float* __restrict__ out, int G)
{
    __shared__ float z[1024 * 10];
    __shared__ float red[2][10];

    float psum[10], psq[10];
#pragma unroll
    for (int j = 0; j < 10; ++j) { psum[j] = 0.f; psq[j] = 0.f; }

    for (int g = threadIdx.x; g < G; g += 256) {
        float gin[16];
        gin[0] = u[g];
        const float* src = g_acc + (size_t)g * 16;
        float inv = 1.f / fmaxf(src[15], 1.f);
#pragma unroll
        for (int j = 0; j < 15; ++j) gin[1 + j] = src[j] * inv;

        float h[50];
#pragma unroll
        for (int j = 0; j < 50; ++j) h[j] = gb1[j];
#pragma unroll
        for (int i = 0; i < 16; ++i) {
            float v = gin[i];
#pragma unroll
            for (int j = 0; j < 50; ++j) h[j] = fmaf(v, gw1[i*50+j], h[j]);
        }
#pragma unroll
        for (int j = 0; j < 50; ++j) h[j] = fmaxf(h[j], 0.f);

        float u2[15];
#pragma unroll
        for (int j = 0; j < 15; ++j) u2[j] = gb2[j];
#pragma unroll
        for (int i = 0; i < 50; ++i) {
            float v = h[i];
#pragma unroll
            for (int j = 0; j < 15; ++j) u2[j] = fmaf(v, gw2[i*15+j], u2[j]);
        }

#pragma unroll
        for (int j = 0; j < 10; ++j) {
            float acc = f1b[j];
#pragma unroll
            for (int i = 0; i < 15; ++i) acc = fmaf(u2[i], f1w[i*10+j], acc);
            z[g*10 + j] = acc;
            psum[j] += acc;
            psq[j]  += acc * acc;
        }
    }

    if (threadIdx.x == 0) {
#pragma unroll
        for (int j = 0; j < 10; ++j) { red[0][j] = 0.f; red[1][j] = 0.f; }
    }
    __syncthreads();
#pragma unroll
    for (int j = 0; j < 10; ++j) {
        atomicAdd(&red[0][j], psum[j]);
        atomicAdd(&red[1][j], psq[j]);
    }
    __syncthreads();

    float mean[10], rstd[10];
    float invG = 1.f / (float)G;
#pragma unroll
    for (int j = 0; j < 10; ++j) {
        mean[j] = red[0][j] * invG;
        float var = red[1][j] * invG - mean[j] * mean[j];
        rstd[j] = rsqrtf(var + 1e-5f);
    }

    for (int g = threadIdx.x; g < G; g += 256) {
        float l[6];
#pragma unroll
        for (int k = 0; k < 6; ++k) l[k] = f2b[k];
#pragma unroll
        for (int j = 0; j < 10; ++j) {
            float zn = (z[g*10 + j] - mean[j]) * rstd[j] * bng[j] + bnb[j];
            zn = fmaxf(zn, 0.f);
#pragma unroll
            for (int k = 0; k < 6; ++k) l[k] = fmaf(zn, f2w[j*6+k], l[k]);
        }
        float m = l[0];
#pragma unroll
        for (int k = 1; k < 6; ++k) m = fmaxf(m, l[k]);
        float s = 0.f;
#pragma unroll
        for (int k = 0; k < 6; ++k) s += expf(l[k] - m);
        float lse = m + logf(s);
#pragma unroll
        for (int k = 0; k < 6; ++k) out[g*6 + k] = l[k] - lse;
    }
}

extern "C" void kernel_launch(void* const* d_in, const int* in_sizes, int n_in,
                              void* d_out, int out_size, void* d_ws, size_t ws_size,
                              hipStream_t stream)
{
    const float* x   = (const float*)d_in[0];
    const int*   ei  = (const int*)d_in[1];
    const float* ea  = (const float*)d_in[2];
    const float* u   = (const float*)d_in[3];
    const int* batch = (const int*)d_in[4];
    const float* ew1 = (const float*)d_in[5];
    const float* eb1 = (const float*)d_in[6];
    const float* ew2 = (const float*)d_in[7];
    const float* eb2 = (const float*)d_in[8];
    const float* nw1 = (const float*)d_in[9];
    const float* nb1 = (const float*)d_in[10];
    const float* nw2 = (const float*)d_in[11];
    const float* nb2 = (const float*)d_in[12];
    const float* gw1 = (const float*)d_in[13];
    const float* gb1 = (const float*)d_in[14];
    const float* gw2 = (const float*)d_in[15];
    const float* gb2 = (const float*)d_in[16];
    const float* f1w = (const float*)d_in[17];
    const float* f1b = (const float*)d_in[18];
    const float* bng = (const float*)d_in[19];
    const float* bnb = (const float*)d_in[20];
    const float* f2w = (const float*)d_in[21];
    const float* f2b = (const float*)d_in[22];

    int N = in_sizes[0] / 3;
    int E = in_sizes[1] / 2;
    int G = in_sizes[3];
    int nb = (N + 1023) / 1024;

    // Plan A needs the full float4 payload array; plan B only perm indices.
    size_t fixed = (size_t)N * 16                      // xp
                 + ((size_t)3 * N + 1) * 4             // cnt, off, cur
                 + (size_t)nb * 8                      // bsum, boff
                 + (size_t)G * 64;                     // g_acc
    size_t needA = (size_t)E * 16 + fixed;
    bool planA = (ws_size >= needA);

    char* p = (char*)d_ws;
    float4* data = nullptr; uint* perm = nullptr;
    if (planA) { data = (float4*)p; p += (size_t)E * 16; }
    float4* xp = (float4*)p;            p += (size_t)N * 16;
    if (!planA) { perm = (uint*)p;      p += (size_t)E * 4; }
    uint* cnt  = (uint*)p;              p += (size_t)N * 4;
    uint* off  = (uint*)p;              p += ((size_t)N + 1) * 4;
    uint* cur  = (uint*)p;              p += (size_t)N * 4;
    uint* bsum = (uint*)p;              p += (size_t)nb * 4;
    uint* boff = (uint*)p;              p += (size_t)nb * 4;
    float* g_acc = (float*)p;

    (void)hipMemsetAsync(cnt, 0, sizeof(uint) * (size_t)N, stream);
    (void)hipMemsetAsync(g_acc, 0, sizeof(float) * (size_t)G * 16, stream);

    prep_kernel<<<(N + 255) / 256, 256, 0, stream>>>(x, xp, N);
    hist_kernel<<<(E + 255) / 256, 256, 0, stream>>>(ei, cnt, E);
    bsum_kernel<<<nb, 256, 0, stream>>>(cnt, bsum, N);
    scan_small_kernel<<<1, 1024, 0, stream>>>(bsum, boff, off, nb, N, E);
    scan_final_kernel<<<nb, 256, 0, stream>>>(cnt, boff, off, cur, N);

    if (planA) {
        scatter_payload_kernel<<<(E + 255) / 256, 256, 0, stream>>>(
            ei, ea, cur, data, E);
        node_kernel<true><<<(N + NPB - 1) / NPB, TPB, 0, stream>>>(
            xp, data, perm, ei, ea, off, batch,
            ew1, eb1, ew2, eb2, nw1, nb1, nw2, nb2, g_acc, N, E);
    } else {
        scatter_perm_kernel<<<(E + 255) / 256, 256, 0, stream>>>(
            ei, cur, perm, E);
        node_kernel<false><<<(N + NPB - 1) / NPB, TPB, 0, stream>>>(
            xp, data, perm, ei, ea, off, batch,
            ew1, eb1, ew2, eb2, nw1, nb1, nw2, nb2, g_acc, N, E);
    }

    global_head_kernel<<<1, 256, 0, stream>>>(
        g_acc, u, gw1, gb1, gw2, gb2, f1w, f1b, bng, bnb, f2w, f2b,
        (float*)d_out, G);
}